// Round 1
// baseline (1769.583 us; speedup 1.0000x reference)
//
#include <hip/hip_runtime.h>
#include <hip/hip_bf16.h>
#include <cstddef>

// LinearAttention: B=4, S=4096, D=1024, H=16, Hd=64
// M = B*S = 16384 rows. All projections are [M,1024]x[1024,1024] GEMMs.
// Round 1: pure fp32 (vector ALU) implementation for correctness + baseline.

#define LDS_P 136   // LDS pitch in floats for GEMM tiles (136*4 B = 544 = 16*34, 16B-aligned rows)

// ---------------------------------------------------------------------------
// Shared GEMM body: C_tile(128x128) = A[M,1024] x B[1024,1024], K=1024, BK=16.
// 256 threads, each computes 8x8 (two 4-wide chunks per dim at +0 / +64).
// ---------------------------------------------------------------------------
__device__ __forceinline__ void gemm_body(const float* __restrict__ A,
                                          const float* __restrict__ B,
                                          int mbase, int nbase,
                                          float* __restrict__ As,
                                          float* __restrict__ Bs,
                                          float acc[8][8])
{
    const int t  = threadIdx.x;
    const int tx = t & 15;
    const int ty = t >> 4;

    for (int kt = 0; kt < 1024; kt += 16) {
        // --- stage A tile (128 rows x 16 k) transposed into As[k][m], and
        // --- B tile (16 k x 128 n) into Bs[k][n]. 512 float4 slots each.
#pragma unroll
        for (int i = 0; i < 2; i++) {
            int slot = t + i * 256;
            int arow = slot >> 2, ac4 = slot & 3;
            float4 a = *(const float4*)(A + (size_t)(mbase + arow) * 1024 + kt + ac4 * 4);
            As[(ac4 * 4 + 0) * LDS_P + arow] = a.x;
            As[(ac4 * 4 + 1) * LDS_P + arow] = a.y;
            As[(ac4 * 4 + 2) * LDS_P + arow] = a.z;
            As[(ac4 * 4 + 3) * LDS_P + arow] = a.w;
            int brow = slot >> 5, bc4 = slot & 31;
            float4 b = *(const float4*)(B + (size_t)(kt + brow) * 1024 + nbase + bc4 * 4);
            *(float4*)(Bs + brow * LDS_P + bc4 * 4) = b;
        }
        __syncthreads();

#pragma unroll
        for (int k = 0; k < 16; k++) {
            float4 a0 = *(const float4*)(As + k * LDS_P + tx * 4);
            float4 a1 = *(const float4*)(As + k * LDS_P + 64 + tx * 4);
            float4 b0 = *(const float4*)(Bs + k * LDS_P + ty * 4);
            float4 b1 = *(const float4*)(Bs + k * LDS_P + 64 + ty * 4);
            float av[8] = {a0.x, a0.y, a0.z, a0.w, a1.x, a1.y, a1.z, a1.w};
            float bv[8] = {b0.x, b0.y, b0.z, b0.w, b1.x, b1.y, b1.z, b1.w};
#pragma unroll
            for (int i = 0; i < 8; i++)
#pragma unroll
                for (int j = 0; j < 8; j++)
                    acc[i][j] = fmaf(av[i], bv[j], acc[i][j]);
        }
        __syncthreads();
    }
}

// ---------------------------------------------------------------------------
// Kernel 1: fused QKV projection. grid = (128 mtiles, 24 ntiles).
// ntile 0..7 -> q (elu+1), 8..15 -> k (elu+1), 16..23 -> v (plain)
// ---------------------------------------------------------------------------
__global__ __launch_bounds__(256) void gemm_qkv(
    const float* __restrict__ x,
    const float* __restrict__ Wq, const float* __restrict__ bq,
    const float* __restrict__ Wk, const float* __restrict__ bk,
    const float* __restrict__ Wv, const float* __restrict__ bv,
    float* __restrict__ qf, float* __restrict__ kf, float* __restrict__ vout)
{
    __shared__ float As[16 * LDS_P];
    __shared__ float Bs[16 * LDS_P];
    float acc[8][8];
#pragma unroll
    for (int i = 0; i < 8; i++)
#pragma unroll
        for (int j = 0; j < 8; j++) acc[i][j] = 0.f;

    const int mt = blockIdx.x;
    const int nt = blockIdx.y;
    const int which = nt >> 3;      // 0=q 1=k 2=v
    const int ntile = nt & 7;

    const float* W    = (which == 0) ? Wq : (which == 1) ? Wk : Wv;
    const float* bias = (which == 0) ? bq : (which == 1) ? bk : bv;
    float* outp       = (which == 0) ? qf : (which == 1) ? kf : vout;
    const bool feat   = (which < 2);

    gemm_body(x, W, mt * 128, ntile * 128, As, Bs, acc);

    const int t = threadIdx.x, tx = t & 15, ty = t >> 4;
#pragma unroll
    for (int i = 0; i < 8; i++) {
        int row = mt * 128 + ((i < 4) ? (tx * 4 + i) : (64 + tx * 4 + i - 4));
#pragma unroll
        for (int jh = 0; jh < 2; jh++) {
            int col = ntile * 128 + ((jh == 0) ? (ty * 4) : (64 + ty * 4));
            float vals[4];
#pragma unroll
            for (int j = 0; j < 4; j++) {
                float vv = acc[i][jh * 4 + j] + bias[col + j];
                if (feat) vv = (vv > 0.f) ? (vv + 1.f) : __expf(vv);
                vals[j] = vv;
            }
            *(float4*)(outp + (size_t)row * 1024 + col) =
                make_float4(vals[0], vals[1], vals[2], vals[3]);
        }
    }
}

// ---------------------------------------------------------------------------
// Kernel 2: kv[n,h,m,d] = sum_s kf[n,s,h,d]*v[n,s,h,m];  ksum[n,h,d] = sum_s kf
// grid = (64 bh, 8 s-chunks of 512). Atomic accumulation into ws.
// ---------------------------------------------------------------------------
__global__ __launch_bounds__(256) void kv_ksum(
    const float* __restrict__ kf, const float* __restrict__ v,
    float* __restrict__ kv, float* __restrict__ ksum)
{
    const int bh = blockIdx.x;          // 0..63 ; n = bh>>4, h = bh&15
    const int n = bh >> 4, h = bh & 15;
    const int chunk = blockIdx.y;       // 0..7, 512 s each
    const int t = threadIdx.x;
    const int d = t & 63;
    const int mg = t >> 6;              // 0..3 (m-group of 16)
    const int sl = t >> 6;              // lane's staging row

    __shared__ float kfs[4][64];
    __shared__ float vs[4][64];

    float acc[16];
#pragma unroll
    for (int i = 0; i < 16; i++) acc[i] = 0.f;
    float ks = 0.f;

    const size_t rowbase = ((size_t)n * 4096 + (size_t)chunk * 512) * 1024 + h * 64;

    for (int s0 = 0; s0 < 512; s0 += 4) {
        kfs[sl][d] = kf[rowbase + (size_t)(s0 + sl) * 1024 + d];
        vs[sl][d]  = v [rowbase + (size_t)(s0 + sl) * 1024 + d];
        __syncthreads();
#pragma unroll
        for (int s2 = 0; s2 < 4; s2++) {
            float kd = kfs[s2][d];
            ks += kd;
#pragma unroll
            for (int mi = 0; mi < 16; mi++)
                acc[mi] = fmaf(vs[s2][mg * 16 + mi], kd, acc[mi]);
        }
        __syncthreads();
    }

#pragma unroll
    for (int mi = 0; mi < 16; mi++)
        atomicAdd(&kv[(size_t)bh * 4096 + (size_t)(mg * 16 + mi) * 64 + d], acc[mi]);
    if (mg == 0)
        atomicAdd(&ksum[bh * 64 + d], ks);
}

// ---------------------------------------------------------------------------
// Kernel 3: y[l,h,m] = z * sum_d qf[l,h,d]*kv[h,m,d], z = 1/(qf . ksum + eps)
// Written IN PLACE over qf (each block owns its tile exclusively).
// grid = (64 ltiles, 16 h, 4 n)
// ---------------------------------------------------------------------------
__global__ __launch_bounds__(256) void y_kernel(
    float* __restrict__ qf,
    const float* __restrict__ kv, const float* __restrict__ ksum)
{
    const int lt = blockIdx.x;
    const int h  = blockIdx.y;
    const int n  = blockIdx.z;
    const int bh = n * 16 + h;
    const int t  = threadIdx.x;

    __shared__ float qs[64 * 65];
    __shared__ float kvs[64 * 65];
    __shared__ float kss[64];

    const size_t rowbase = ((size_t)n * 4096 + (size_t)lt * 64) * 1024 + h * 64;

#pragma unroll
    for (int i = 0; i < 4; i++) {
        int slot = t + i * 256;         // 0..1023
        int l = slot >> 4, c4 = slot & 15;
        float4 q4 = *(const float4*)(qf + rowbase + (size_t)l * 1024 + c4 * 4);
        qs[l * 65 + c4 * 4 + 0] = q4.x;
        qs[l * 65 + c4 * 4 + 1] = q4.y;
        qs[l * 65 + c4 * 4 + 2] = q4.z;
        qs[l * 65 + c4 * 4 + 3] = q4.w;
        float4 k4 = *(const float4*)(kv + (size_t)bh * 4096 + slot * 4);
        // kv element index = m*64+d ; slot*4 covers it contiguously: m = slot>>4, d0 = (slot&15)*4
        kvs[l * 65 + c4 * 4 + 0] = k4.x;   // here l==m, c4*4==d0
        kvs[l * 65 + c4 * 4 + 1] = k4.y;
        kvs[l * 65 + c4 * 4 + 2] = k4.z;
        kvs[l * 65 + c4 * 4 + 3] = k4.w;
    }
    if (t < 64) kss[t] = ksum[bh * 64 + t];
    __syncthreads();

    const int l  = t & 63;
    const int mg = t >> 6;

    float zden = 0.f;
#pragma unroll 8
    for (int d = 0; d < 64; d++) zden += qs[l * 65 + d] * kss[d];
    const float z = 1.0f / (zden + 1e-6f);

    float acc[16];
#pragma unroll
    for (int i = 0; i < 16; i++) acc[i] = 0.f;

    for (int d = 0; d < 64; d++) {
        float qd = qs[l * 65 + d];
#pragma unroll
        for (int mi = 0; mi < 16; mi++)
            acc[mi] = fmaf(qd, kvs[(mg * 16 + mi) * 65 + d], acc[mi]);
    }

    __syncthreads();   // everyone done reading qs before overwrite
#pragma unroll
    for (int mi = 0; mi < 16; mi++)
        qs[l * 65 + mg * 16 + mi] = acc[mi] * z;
    __syncthreads();

    // coalesced write-back of y over the qf tile
#pragma unroll
    for (int i = 0; i < 4; i++) {
        int slot = t + i * 256;
        int l2 = slot >> 4, c4 = slot & 15;
        float4 o = make_float4(qs[l2 * 65 + c4 * 4 + 0],
                               qs[l2 * 65 + c4 * 4 + 1],
                               qs[l2 * 65 + c4 * 4 + 2],
                               qs[l2 * 65 + c4 * 4 + 3]);
        *(float4*)(qf + rowbase + (size_t)l2 * 1024 + c4 * 4) = o;
    }
}

// ---------------------------------------------------------------------------
// Kernel 4: out = y @ Wo + bo. grid = (128 mtiles, 8 ntiles)
// ---------------------------------------------------------------------------
__global__ __launch_bounds__(256) void gemm_out(
    const float* __restrict__ y, const float* __restrict__ Wo,
    const float* __restrict__ bo, float* __restrict__ out)
{
    __shared__ float As[16 * LDS_P];
    __shared__ float Bs[16 * LDS_P];
    float acc[8][8];
#pragma unroll
    for (int i = 0; i < 8; i++)
#pragma unroll
        for (int j = 0; j < 8; j++) acc[i][j] = 0.f;

    const int mt = blockIdx.x;
    const int ntile = blockIdx.y;

    gemm_body(y, Wo, mt * 128, ntile * 128, As, Bs, acc);

    const int t = threadIdx.x, tx = t & 15, ty = t >> 4;
#pragma unroll
    for (int i = 0; i < 8; i++) {
        int row = mt * 128 + ((i < 4) ? (tx * 4 + i) : (64 + tx * 4 + i - 4));
#pragma unroll
        for (int jh = 0; jh < 2; jh++) {
            int col = ntile * 128 + ((jh == 0) ? (ty * 4) : (64 + ty * 4));
            float4 o = make_float4(acc[i][jh * 4 + 0] + bo[col + 0],
                                   acc[i][jh * 4 + 1] + bo[col + 1],
                                   acc[i][jh * 4 + 2] + bo[col + 2],
                                   acc[i][jh * 4 + 3] + bo[col + 3]);
            *(float4*)(out + (size_t)row * 1024 + col) = o;
        }
    }
}

// ---------------------------------------------------------------------------
__global__ __launch_bounds__(256) void zero_f(float* __restrict__ p, int n)
{
    int i = blockIdx.x * 256 + threadIdx.x;
    if (i < n) p[i] = 0.f;
}

extern "C" void kernel_launch(void* const* d_in, const int* in_sizes, int n_in,
                              void* d_out, int out_size, void* d_ws, size_t ws_size,
                              hipStream_t stream)
{
    const float* x  = (const float*)d_in[0];
    const float* Wq = (const float*)d_in[1];
    const float* bq = (const float*)d_in[2];
    const float* Wk = (const float*)d_in[3];
    const float* bk = (const float*)d_in[4];
    const float* Wv = (const float*)d_in[5];
    const float* bv = (const float*)d_in[6];
    const float* Wo = (const float*)d_in[7];
    const float* bo = (const float*)d_in[8];
    float* out = (float*)d_out;

    float* ws   = (float*)d_ws;
    float* qf   = ws;                      // 16777216 floats (also y, in place)
    float* kf   = ws + (size_t)16777216;   // 16777216
    float* v    = ws + (size_t)2 * 16777216;
    float* kv   = ws + (size_t)3 * 16777216;   // 64*64*64 = 262144
    float* ksum = kv + 262144;                 // 4096

    // zero kv + ksum (266240 floats)
    zero_f<<<dim3(1040), dim3(256), 0, stream>>>(kv, 266240);

    gemm_qkv<<<dim3(128, 24), dim3(256), 0, stream>>>(x, Wq, bq, Wk, bk, Wv, bv, qf, kf, v);
    kv_ksum<<<dim3(64, 8), dim3(256), 0, stream>>>(kf, v, kv, ksum);
    y_kernel<<<dim3(64, 16, 4), dim3(256), 0, stream>>>(qf, kv, ksum);
    gemm_out<<<dim3(128, 8), dim3(256), 0, stream>>>(qf, Wo, bo, out);
}

// Round 2
// 465.390 us; speedup vs baseline: 3.8024x; 3.8024x over previous
//
#include <hip/hip_runtime.h>
#include <cstddef>
#include <cstdint>

// LinearAttention B=4,S=4096,D=1024,H=16,Hd=64.  M=16384.
// Round 2: bf16 MFMA (16x16x32) for the two big GEMMs (m97 structure:
// 128x128 tile, BK=32, global_load_lds width=16, 4 waves x 4x4 fragments).
// kv/ksum + y stay fp32 VALU with bf16 I/O.

typedef __attribute__((ext_vector_type(8))) __bf16 bf16x8;
typedef __attribute__((ext_vector_type(4))) __bf16 bf16x4;
typedef __attribute__((ext_vector_type(4))) float f32x4;

__device__ __forceinline__ void async_cp16(const void* g, void* s) {
    // LDS dest is wave-uniform base; HW writes lane i at base + i*16.
    __builtin_amdgcn_global_load_lds(
        (__attribute__((address_space(1))) void*)g,
        (__attribute__((address_space(3))) void*)s, 16, 0, 0);
}

// ---------------------------------------------------------------------------
// Core: 128x128 C-tile of A[16384,1024]_bf16 x BT[1024,1024]_bf16^T.
// 256 threads (4 waves as 2x2 of 64x64), K=1024, BK=32.
// ---------------------------------------------------------------------------
__device__ __forceinline__ void mfma_core(const __bf16* __restrict__ A,
                                          const __bf16* __restrict__ BT,
                                          int mbase, int nbase,
                                          __bf16* As, __bf16* Bs,
                                          f32x4 acc[4][4])
{
    const int t    = threadIdx.x;
    const int lane = t & 63;
    const int wid  = t >> 6;
    const int wm   = (wid >> 1) * 64;
    const int wn   = (wid & 1) * 64;
    const int fr   = lane & 15;   // m (or n) within 16x16 tile
    const int fq   = lane >> 4;   // quad -> k block of 8
    // staging decomposition: chunk c (1 KiB = 16 rows x 32 k), lane i ->
    // row 16c+(i>>2), k-off (i&3)*8 ; lds elem = c*512 + i*8 (HW-implied)
    const int srow = lane >> 2;
    const int skof = (lane & 3) * 8;

    const __bf16* arow0 = A  + (size_t)(mbase + wid * 32 + srow) * 1024 + skof;
    const __bf16* brow0 = BT + (size_t)(nbase + wid * 32 + srow) * 1024 + skof;

    for (int kt = 0; kt < 1024; kt += 32) {
        // wave wid stages As chunks {2wid,2wid+1} and Bs chunks {2wid,2wid+1}
        async_cp16(arow0 + kt,        As + (2 * wid + 0) * 512);
        async_cp16(arow0 + kt + 16 * 1024, As + (2 * wid + 1) * 512);
        async_cp16(brow0 + kt,        Bs + (2 * wid + 0) * 512);
        async_cp16(brow0 + kt + 16 * 1024, Bs + (2 * wid + 1) * 512);
        __syncthreads();

        bf16x8 af[4], bfr[4];
#pragma unroll
        for (int i = 0; i < 4; i++) {
            af[i]  = *(const bf16x8*)(As + (wm + i * 16 + fr) * 32 + fq * 8);
            bfr[i] = *(const bf16x8*)(Bs + (wn + i * 16 + fr) * 32 + fq * 8);
        }
#pragma unroll
        for (int i = 0; i < 4; i++)
#pragma unroll
            for (int j = 0; j < 4; j++)
                acc[i][j] = __builtin_amdgcn_mfma_f32_16x16x32_bf16(
                    af[i], bfr[j], acc[i][j], 0, 0, 0);
        __syncthreads();
    }
}

// ---------------------------------------------------------------------------
// Kernel: fused QKV. grid=(128 mt, 24 nt); nt>>3: 0=q(fp32,elu+1) 1=k(bf16,
// elu+1) 2=v(bf16).
// ---------------------------------------------------------------------------
__global__ __launch_bounds__(256) void gemm_qkv_mfma(
    const __bf16* __restrict__ xb,
    const __bf16* __restrict__ wqt, const __bf16* __restrict__ wkt,
    const __bf16* __restrict__ wvt,
    const float* __restrict__ bq, const float* __restrict__ bk,
    const float* __restrict__ bv,
    float* __restrict__ qf, __bf16* __restrict__ kfb, __bf16* __restrict__ vb)
{
    __shared__ __bf16 As[128 * 32];
    __shared__ __bf16 Bs[128 * 32];
    f32x4 acc[4][4];
#pragma unroll
    for (int i = 0; i < 4; i++)
#pragma unroll
        for (int j = 0; j < 4; j++) acc[i][j] = (f32x4){0.f, 0.f, 0.f, 0.f};

    const int mt = blockIdx.x;
    const int nt = blockIdx.y;
    const int which = nt >> 3;
    const int nbase = (nt & 7) * 128;
    const int mbase = mt * 128;

    const __bf16* BT  = (which == 0) ? wqt : (which == 1) ? wkt : wvt;
    const float* bias = (which == 0) ? bq : (which == 1) ? bk : bv;

    mfma_core(xb, BT, mbase, nbase, As, Bs, acc);

    const int t = threadIdx.x, lane = t & 63, wid = t >> 6;
    const int wm = (wid >> 1) * 64, wn = (wid & 1) * 64;
    const int fr = lane & 15, fq = lane >> 4;

#pragma unroll
    for (int i = 0; i < 4; i++)
#pragma unroll
        for (int j = 0; j < 4; j++) {
            const int col = nbase + wn + j * 16 + fr;
            const float bval = bias[col];
#pragma unroll
            for (int r = 0; r < 4; r++) {
                const int row = mbase + wm + i * 16 + fq * 4 + r;
                float vv = acc[i][j][r] + bval;
                if (which < 2) vv = (vv > 0.f) ? (vv + 1.f) : __expf(vv);
                const size_t idx = (size_t)row * 1024 + col;
                if (which == 0)      qf[idx]  = vv;
                else if (which == 1) kfb[idx] = (__bf16)vv;
                else                 vb[idx]  = (__bf16)vv;
            }
        }
}

// ---------------------------------------------------------------------------
// Kernel: out = y_bf16 @ WoT + bo (fp32 out). grid=(128 mt, 8 nt)
// ---------------------------------------------------------------------------
__global__ __launch_bounds__(256) void gemm_out_mfma(
    const __bf16* __restrict__ yb, const __bf16* __restrict__ wot,
    const float* __restrict__ bo, float* __restrict__ out)
{
    __shared__ __bf16 As[128 * 32];
    __shared__ __bf16 Bs[128 * 32];
    f32x4 acc[4][4];
#pragma unroll
    for (int i = 0; i < 4; i++)
#pragma unroll
        for (int j = 0; j < 4; j++) acc[i][j] = (f32x4){0.f, 0.f, 0.f, 0.f};

    const int mbase = blockIdx.x * 128;
    const int nbase = blockIdx.y * 128;

    mfma_core(yb, wot, mbase, nbase, As, Bs, acc);

    const int t = threadIdx.x, lane = t & 63, wid = t >> 6;
    const int wm = (wid >> 1) * 64, wn = (wid & 1) * 64;
    const int fr = lane & 15, fq = lane >> 4;

#pragma unroll
    for (int i = 0; i < 4; i++)
#pragma unroll
        for (int j = 0; j < 4; j++) {
            const int col = nbase + wn + j * 16 + fr;
            const float bval = bo[col];
#pragma unroll
            for (int r = 0; r < 4; r++) {
                const int row = mbase + wm + i * 16 + fq * 4 + r;
                out[(size_t)row * 1024 + col] = acc[i][j][r] + bval;
            }
        }
}

// ---------------------------------------------------------------------------
// cast x fp32 -> bf16 (16777216 elements, 8/thread)
// ---------------------------------------------------------------------------
__global__ __launch_bounds__(256) void cast_x(const float* __restrict__ x,
                                              __bf16* __restrict__ xb)
{
    const size_t i = ((size_t)blockIdx.x * 256 + threadIdx.x) * 8;
    float4 a = *(const float4*)(x + i);
    float4 b = *(const float4*)(x + i + 4);
    bf16x8 o;
    o[0] = (__bf16)a.x; o[1] = (__bf16)a.y; o[2] = (__bf16)a.z; o[3] = (__bf16)a.w;
    o[4] = (__bf16)b.x; o[5] = (__bf16)b.y; o[6] = (__bf16)b.z; o[7] = (__bf16)b.w;
    *(bf16x8*)(xb + i) = o;
}

// ---------------------------------------------------------------------------
// transpose 1024x1024 fp32 -> bf16 transposed.  grid=(32 kt, 32 ntile, 4 w)
// ---------------------------------------------------------------------------
__global__ __launch_bounds__(256) void transpose_w(
    const float* __restrict__ w0, const float* __restrict__ w1,
    const float* __restrict__ w2, const float* __restrict__ w3,
    __bf16* __restrict__ o0, __bf16* __restrict__ o1,
    __bf16* __restrict__ o2, __bf16* __restrict__ o3)
{
    __shared__ float ld[32][33];
    const int wsel = blockIdx.z;
    const float* src = (wsel == 0) ? w0 : (wsel == 1) ? w1 : (wsel == 2) ? w2 : w3;
    __bf16* dst      = (wsel == 0) ? o0 : (wsel == 1) ? o1 : (wsel == 2) ? o2 : o3;

    const int kbase = blockIdx.x * 32;
    const int nbase = blockIdx.y * 32;
    const int t = threadIdx.x;
    const int r = t >> 3, c4 = (t & 7) * 4;

    float4 a = *(const float4*)(src + (size_t)(kbase + r) * 1024 + nbase + c4);
    ld[r][c4 + 0] = a.x; ld[r][c4 + 1] = a.y; ld[r][c4 + 2] = a.z; ld[r][c4 + 3] = a.w;
    __syncthreads();

    bf16x4 o;
    o[0] = (__bf16)ld[c4 + 0][r];
    o[1] = (__bf16)ld[c4 + 1][r];
    o[2] = (__bf16)ld[c4 + 2][r];
    o[3] = (__bf16)ld[c4 + 3][r];
    *(bf16x4*)(dst + (size_t)(nbase + r) * 1024 + kbase + c4) = o;
}

// ---------------------------------------------------------------------------
// kv[n,h,m,d] = sum_s kf*v ; ksum[n,h,d] = sum_s kf.  bf16 inputs, fp32 acc.
// grid=(64 bh, 8 chunks of 512 s)
// ---------------------------------------------------------------------------
__global__ __launch_bounds__(256) void kv_ksum(
    const __bf16* __restrict__ kfb, const __bf16* __restrict__ vb,
    float* __restrict__ kv, float* __restrict__ ksum)
{
    const int bh = blockIdx.x;
    const int n = bh >> 4, h = bh & 15;
    const int chunk = blockIdx.y;
    const int t = threadIdx.x;
    const int d = t & 63;
    const int mg = t >> 6;
    const int sl = t >> 6;

    __shared__ float kfs[4][64];
    __shared__ float vs[4][64];

    float acc[16];
#pragma unroll
    for (int i = 0; i < 16; i++) acc[i] = 0.f;
    float ks = 0.f;

    const size_t rowbase = ((size_t)n * 4096 + (size_t)chunk * 512) * 1024 + h * 64;

    for (int s0 = 0; s0 < 512; s0 += 4) {
        kfs[sl][d] = (float)kfb[rowbase + (size_t)(s0 + sl) * 1024 + d];
        vs[sl][d]  = (float)vb [rowbase + (size_t)(s0 + sl) * 1024 + d];
        __syncthreads();
#pragma unroll
        for (int s2 = 0; s2 < 4; s2++) {
            float kd = kfs[s2][d];
            ks += kd;
#pragma unroll
            for (int mi = 0; mi < 16; mi++)
                acc[mi] = fmaf(vs[s2][mg * 16 + mi], kd, acc[mi]);
        }
        __syncthreads();
    }

#pragma unroll
    for (int mi = 0; mi < 16; mi++)
        atomicAdd(&kv[(size_t)bh * 4096 + (size_t)(mg * 16 + mi) * 64 + d], acc[mi]);
    if (mg == 0)
        atomicAdd(&ksum[bh * 64 + d], ks);
}

// ---------------------------------------------------------------------------
// y[l,h,m] = z * sum_d qf*kv ; z = 1/(qf.ksum+eps).  qf fp32 in, y bf16 out.
// grid=(64 lt, 16 h, 4 n)
// ---------------------------------------------------------------------------
__global__ __launch_bounds__(256) void y_kernel(
    const float* __restrict__ qf, const float* __restrict__ kv,
    const float* __restrict__ ksum, __bf16* __restrict__ yb)
{
    const int lt = blockIdx.x;
    const int h  = blockIdx.y;
    const int n  = blockIdx.z;
    const int bh = n * 16 + h;
    const int t  = threadIdx.x;

    __shared__ float qs[64 * 65];
    __shared__ float kvs[64 * 65];
    __shared__ float kss[64];

    const size_t rowbase = ((size_t)n * 4096 + (size_t)lt * 64) * 1024 + h * 64;

#pragma unroll
    for (int i = 0; i < 4; i++) {
        int slot = t + i * 256;
        int l = slot >> 4, c4 = slot & 15;
        float4 q4 = *(const float4*)(qf + rowbase + (size_t)l * 1024 + c4 * 4);
        qs[l * 65 + c4 * 4 + 0] = q4.x;
        qs[l * 65 + c4 * 4 + 1] = q4.y;
        qs[l * 65 + c4 * 4 + 2] = q4.z;
        qs[l * 65 + c4 * 4 + 3] = q4.w;
        float4 k4 = *(const float4*)(kv + (size_t)bh * 4096 + slot * 4);
        kvs[l * 65 + c4 * 4 + 0] = k4.x;  // l==m here, c4*4==d0
        kvs[l * 65 + c4 * 4 + 1] = k4.y;
        kvs[l * 65 + c4 * 4 + 2] = k4.z;
        kvs[l * 65 + c4 * 4 + 3] = k4.w;
    }
    if (t < 64) kss[t] = ksum[bh * 64 + t];
    __syncthreads();

    const int l  = t & 63;
    const int mg = t >> 6;

    float zden = 0.f;
#pragma unroll 8
    for (int d = 0; d < 64; d++) zden += qs[l * 65 + d] * kss[d];
    const float z = 1.0f / (zden + 1e-6f);

    float acc[16];
#pragma unroll
    for (int i = 0; i < 16; i++) acc[i] = 0.f;

    for (int d = 0; d < 64; d++) {
        float qd = qs[l * 65 + d];
#pragma unroll
        for (int mi = 0; mi < 16; mi++)
            acc[mi] = fmaf(qd, kvs[(mg * 16 + mi) * 65 + d], acc[mi]);
    }

    __syncthreads();
#pragma unroll
    for (int mi = 0; mi < 16; mi++)
        qs[l * 65 + mg * 16 + mi] = acc[mi] * z;
    __syncthreads();

#pragma unroll
    for (int i = 0; i < 4; i++) {
        int slot = t + i * 256;
        int l2 = slot >> 4, m0 = (slot & 15) * 4;
        bf16x4 o;
        o[0] = (__bf16)qs[l2 * 65 + m0 + 0];
        o[1] = (__bf16)qs[l2 * 65 + m0 + 1];
        o[2] = (__bf16)qs[l2 * 65 + m0 + 2];
        o[3] = (__bf16)qs[l2 * 65 + m0 + 3];
        *(bf16x4*)(yb + rowbase + (size_t)l2 * 1024 + m0) = o;
    }
}

// ---------------------------------------------------------------------------
__global__ __launch_bounds__(256) void zero_f(float* __restrict__ p, int n)
{
    int i = blockIdx.x * 256 + threadIdx.x;
    if (i < n) p[i] = 0.f;
}

extern "C" void kernel_launch(void* const* d_in, const int* in_sizes, int n_in,
                              void* d_out, int out_size, void* d_ws, size_t ws_size,
                              hipStream_t stream)
{
    const float* x  = (const float*)d_in[0];
    const float* Wq = (const float*)d_in[1];
    const float* bq = (const float*)d_in[2];
    const float* Wk = (const float*)d_in[3];
    const float* bk = (const float*)d_in[4];
    const float* Wv = (const float*)d_in[5];
    const float* bv = (const float*)d_in[6];
    const float* Wo = (const float*)d_in[7];
    const float* bo = (const float*)d_in[8];
    float* out = (float*)d_out;

    // workspace layout (bytes): 177.2 MB total
    __bf16* xb  = (__bf16*)d_ws;                    // 16777216 bf16
    __bf16* wqt = xb + (size_t)16777216;            // 1048576 each
    __bf16* wkt = wqt + 1048576;
    __bf16* wvt = wkt + 1048576;
    __bf16* wot = wvt + 1048576;
    float* qf   = (float*)(wot + 1048576);          // 16777216 fp32
    __bf16* kfb = (__bf16*)(qf + (size_t)16777216); // 16777216 bf16 (reused as y)
    __bf16* vb  = kfb + (size_t)16777216;           // 16777216 bf16
    float* kv   = (float*)(vb + (size_t)16777216);  // 262144 fp32
    float* ksum = kv + 262144;                      // 4096 fp32

    zero_f<<<dim3(1040), dim3(256), 0, stream>>>(kv, 266240);
    cast_x<<<dim3(8192), dim3(256), 0, stream>>>(x, xb);
    transpose_w<<<dim3(32, 32, 4), dim3(256), 0, stream>>>(
        Wq, Wk, Wv, Wo, wqt, wkt, wvt, wot);

    gemm_qkv_mfma<<<dim3(128, 24), dim3(256), 0, stream>>>(
        xb, wqt, wkt, wvt, bq, bk, bv, qf, kfb, vb);
    kv_ksum<<<dim3(64, 8), dim3(256), 0, stream>>>(kfb, vb, kv, ksum);
    y_kernel<<<dim3(64, 16, 4), dim3(256), 0, stream>>>(qf, kv, ksum, kfb);
    gemm_out_mfma<<<dim3(128, 8), dim3(256), 0, stream>>>(kfb, wot, bo, out);
}

// Round 3
// 358.082 us; speedup vs baseline: 4.9418x; 1.2997x over previous
//
#include <hip/hip_runtime.h>
#include <cstddef>
#include <cstdint>

// LinearAttention B=4,S=4096,D=1024,H=16,Hd=64.  M=16384.
// Round 3: everything matmul-shaped on MFMA.
//  - gemm_qkv / gemm_out: m97-style 128x128 bf16 MFMA (unchanged structure),
//    qf now stored bf16.
//  - kv_ksum: per-head 64x64xK MFMA over s-chunks, ksum via ones-A MFMA,
//    partials + reduce (no atomics, no zero pass).
//  - y: per-head Mx64x64 MFMA, zden via ksum-replicated-B MFMA (z arrives in
//    the exact C-row lane mapping needed for scaling).

typedef __attribute__((ext_vector_type(8))) __bf16 bf16x8;
typedef __attribute__((ext_vector_type(4))) __bf16 bf16x4;
typedef __attribute__((ext_vector_type(2))) __bf16 bf16x2;
typedef __attribute__((ext_vector_type(4))) float f32x4;

__device__ __forceinline__ void async_cp16(const void* g, void* s) {
    __builtin_amdgcn_global_load_lds(
        (__attribute__((address_space(1))) void*)g,
        (__attribute__((address_space(3))) void*)s, 16, 0, 0);
}

// ---------------------------------------------------------------------------
// 128x128 C-tile of A[.,1024]_bf16 x BT[1024,1024]_bf16^T, K=1024, BK=32.
// ---------------------------------------------------------------------------
__device__ __forceinline__ void mfma_core(const __bf16* __restrict__ A,
                                          const __bf16* __restrict__ BT,
                                          int mbase, int nbase,
                                          __bf16* As, __bf16* Bs,
                                          f32x4 acc[4][4])
{
    const int t    = threadIdx.x;
    const int lane = t & 63;
    const int wid  = t >> 6;
    const int wm   = (wid >> 1) * 64;
    const int wn   = (wid & 1) * 64;
    const int fr   = lane & 15;
    const int fq   = lane >> 4;
    const int srow = lane >> 2;
    const int skof = (lane & 3) * 8;

    const __bf16* arow0 = A  + (size_t)(mbase + wid * 32 + srow) * 1024 + skof;
    const __bf16* brow0 = BT + (size_t)(nbase + wid * 32 + srow) * 1024 + skof;

    for (int kt = 0; kt < 1024; kt += 32) {
        async_cp16(arow0 + kt,             As + (2 * wid + 0) * 512);
        async_cp16(arow0 + kt + 16 * 1024, As + (2 * wid + 1) * 512);
        async_cp16(brow0 + kt,             Bs + (2 * wid + 0) * 512);
        async_cp16(brow0 + kt + 16 * 1024, Bs + (2 * wid + 1) * 512);
        __syncthreads();

        bf16x8 af[4], bfr[4];
#pragma unroll
        for (int i = 0; i < 4; i++) {
            af[i]  = *(const bf16x8*)(As + (wm + i * 16 + fr) * 32 + fq * 8);
            bfr[i] = *(const bf16x8*)(Bs + (wn + i * 16 + fr) * 32 + fq * 8);
        }
#pragma unroll
        for (int i = 0; i < 4; i++)
#pragma unroll
            for (int j = 0; j < 4; j++)
                acc[i][j] = __builtin_amdgcn_mfma_f32_16x16x32_bf16(
                    af[i], bfr[j], acc[i][j], 0, 0, 0);
        __syncthreads();
    }
}

// ---------------------------------------------------------------------------
// QKV: grid=(128 mt, 24 nt); nt>>3: 0=q 1=k (both elu+1) 2=v. All bf16 out.
// ---------------------------------------------------------------------------
__global__ __launch_bounds__(256) void gemm_qkv_mfma(
    const __bf16* __restrict__ xb,
    const __bf16* __restrict__ wqt, const __bf16* __restrict__ wkt,
    const __bf16* __restrict__ wvt,
    const float* __restrict__ bq, const float* __restrict__ bk,
    const float* __restrict__ bv,
    __bf16* __restrict__ qfb, __bf16* __restrict__ kfb, __bf16* __restrict__ vb)
{
    __shared__ __bf16 As[128 * 32];
    __shared__ __bf16 Bs[128 * 32];
    f32x4 acc[4][4];
#pragma unroll
    for (int i = 0; i < 4; i++)
#pragma unroll
        for (int j = 0; j < 4; j++) acc[i][j] = (f32x4){0.f, 0.f, 0.f, 0.f};

    const int mt = blockIdx.x;
    const int nt = blockIdx.y;
    const int which = nt >> 3;
    const int nbase = (nt & 7) * 128;
    const int mbase = mt * 128;

    const __bf16* BT  = (which == 0) ? wqt : (which == 1) ? wkt : wvt;
    const float* bias = (which == 0) ? bq : (which == 1) ? bk : bv;
    __bf16* outp      = (which == 0) ? qfb : (which == 1) ? kfb : vb;
    const bool feat   = (which < 2);

    mfma_core(xb, BT, mbase, nbase, As, Bs, acc);

    const int t = threadIdx.x, lane = t & 63, wid = t >> 6;
    const int wm = (wid >> 1) * 64, wn = (wid & 1) * 64;
    const int fr = lane & 15, fq = lane >> 4;

#pragma unroll
    for (int i = 0; i < 4; i++)
#pragma unroll
        for (int j = 0; j < 4; j++) {
            const int col = nbase + wn + j * 16 + fr;
            const float bval = bias[col];
#pragma unroll
            for (int r = 0; r < 4; r++) {
                const int row = mbase + wm + i * 16 + fq * 4 + r;
                float vv = acc[i][j][r] + bval;
                if (feat) vv = (vv > 0.f) ? (vv + 1.f) : __expf(vv);
                outp[(size_t)row * 1024 + col] = (__bf16)vv;
            }
        }
}

// ---------------------------------------------------------------------------
// out = y @ WoT + bo (fp32). grid=(128 mt, 8 nt)
// ---------------------------------------------------------------------------
__global__ __launch_bounds__(256) void gemm_out_mfma(
    const __bf16* __restrict__ yb, const __bf16* __restrict__ wot,
    const float* __restrict__ bo, float* __restrict__ out)
{
    __shared__ __bf16 As[128 * 32];
    __shared__ __bf16 Bs[128 * 32];
    f32x4 acc[4][4];
#pragma unroll
    for (int i = 0; i < 4; i++)
#pragma unroll
        for (int j = 0; j < 4; j++) acc[i][j] = (f32x4){0.f, 0.f, 0.f, 0.f};

    const int mbase = blockIdx.x * 128;
    const int nbase = blockIdx.y * 128;

    mfma_core(yb, wot, mbase, nbase, As, Bs, acc);

    const int t = threadIdx.x, lane = t & 63, wid = t >> 6;
    const int wm = (wid >> 1) * 64, wn = (wid & 1) * 64;
    const int fr = lane & 15, fq = lane >> 4;

#pragma unroll
    for (int i = 0; i < 4; i++)
#pragma unroll
        for (int j = 0; j < 4; j++) {
            const int col = nbase + wn + j * 16 + fr;
            const float bval = bo[col];
#pragma unroll
            for (int r = 0; r < 4; r++) {
                const int row = mbase + wm + i * 16 + fq * 4 + r;
                out[(size_t)row * 1024 + col] = acc[i][j][r] + bval;
            }
        }
}

// ---------------------------------------------------------------------------
// kv partials: kvp[bh][chunk][m][d] = sum_{s in chunk} v[s][m]*kf[s][d]
// ksum partials via ones-A MFMA.  grid=(64 bh, 16 chunks of 256 s).
// ---------------------------------------------------------------------------
__global__ __launch_bounds__(256) void kv_ksum_mfma(
    const __bf16* __restrict__ kfb, const __bf16* __restrict__ vb,
    float* __restrict__ kvp, float* __restrict__ ksp)
{
    __shared__ __bf16 kfs[64 * 66];
    __shared__ __bf16 vs[64 * 66];

    const int bh = blockIdx.x;
    const int n = bh >> 4, h = bh & 15;
    const int chunk = blockIdx.y;
    const int t = threadIdx.x, lane = t & 63, w = t >> 6;
    const int fr = lane & 15, fq = lane >> 4;

    f32x4 acc[4];
#pragma unroll
    for (int j = 0; j < 4; j++) acc[j] = (f32x4){0.f, 0.f, 0.f, 0.f};
    f32x4 accks = (f32x4){0.f, 0.f, 0.f, 0.f};

    bf16x8 ones;
#pragma unroll
    for (int e = 0; e < 8; e++) ones[e] = (__bf16)1.0f;

    const size_t base = ((size_t)n * 4096 + (size_t)chunk * 256) * 1024 + h * 64;

    for (int tile = 0; tile < 4; tile++) {
#pragma unroll
        for (int i = 0; i < 2; i++) {
            int idx = t + i * 256;              // 0..511
            int s = idx >> 3, d0 = (idx & 7) * 8;
            bf16x8 k8 = *(const bf16x8*)(kfb + base + (size_t)(tile * 64 + s) * 1024 + d0);
            bf16x8 v8 = *(const bf16x8*)(vb  + base + (size_t)(tile * 64 + s) * 1024 + d0);
#pragma unroll
            for (int e = 0; e < 4; e++) {
                *(bf16x2*)(kfs + s * 66 + d0 + 2 * e) = (bf16x2){k8[2*e], k8[2*e+1]};
                *(bf16x2*)(vs  + s * 66 + d0 + 2 * e) = (bf16x2){v8[2*e], v8[2*e+1]};
            }
        }
        __syncthreads();

#pragma unroll
        for (int kk = 0; kk < 2; kk++) {
            bf16x8 af, bfr[4];
#pragma unroll
            for (int j = 0; j < 8; j++)
                af[j] = vs[(kk * 32 + fq * 8 + j) * 66 + 16 * w + fr];
#pragma unroll
            for (int j2 = 0; j2 < 4; j2++)
#pragma unroll
                for (int j = 0; j < 8; j++)
                    bfr[j2][j] = kfs[(kk * 32 + fq * 8 + j) * 66 + 16 * j2 + fr];
#pragma unroll
            for (int j2 = 0; j2 < 4; j2++)
                acc[j2] = __builtin_amdgcn_mfma_f32_16x16x32_bf16(
                    af, bfr[j2], acc[j2], 0, 0, 0);
            accks = __builtin_amdgcn_mfma_f32_16x16x32_bf16(
                ones, bfr[w], accks, 0, 0, 0);
        }
        __syncthreads();
    }

    const size_t pbase = ((size_t)bh * 16 + chunk) * 4096;
#pragma unroll
    for (int j2 = 0; j2 < 4; j2++)
#pragma unroll
        for (int r = 0; r < 4; r++) {
            int m = 16 * w + fq * 4 + r;
            int d = 16 * j2 + fr;
            kvp[pbase + m * 64 + d] = acc[j2][r];
        }
    if (fq == 0)
        ksp[((size_t)bh * 16 + chunk) * 64 + 16 * w + fr] = accks[0];
}

// ---------------------------------------------------------------------------
// reduce partials -> kvb bf16 [bh][m][d], ksumb bf16 [bh][d]
// ---------------------------------------------------------------------------
__global__ __launch_bounds__(256) void reduce_kv(
    const float* __restrict__ kvp, const float* __restrict__ ksp,
    __bf16* __restrict__ kvb, __bf16* __restrict__ ksumb)
{
    const int b = blockIdx.x;
    if (b < 1024) {
        int i = b * 256 + threadIdx.x;          // 0..262143
        int bh = i >> 12, md = i & 4095;
        float s = 0.f;
#pragma unroll
        for (int c = 0; c < 16; c++) s += kvp[((size_t)bh * 16 + c) * 4096 + md];
        kvb[i] = (__bf16)s;
    } else {
        int j = (b - 1024) * 256 + threadIdx.x; // 0..4095
        int bh = j >> 6, d = j & 63;
        float s = 0.f;
#pragma unroll
        for (int c = 0; c < 16; c++) s += ksp[((size_t)bh * 16 + c) * 64 + d];
        ksumb[j] = (__bf16)s;
    }
}

// ---------------------------------------------------------------------------
// y[g,h,m] = z * sum_d qf[g,h,d]*kv[bh,m,d], z = 1/(qf.ksum+eps)
// zden via MFMA with B[k][n] = ksum[k] (replicated) -> lands in C-row mapping.
// grid=(128 gtiles of 128, 16 h)
// ---------------------------------------------------------------------------
__global__ __launch_bounds__(256) void y_mfma(
    const __bf16* __restrict__ qfb, const __bf16* __restrict__ kvb,
    const __bf16* __restrict__ ksumb, __bf16* __restrict__ yb)
{
    __shared__ __bf16 qs[128 * 72];
    __shared__ __bf16 kvs[64 * 72];

    const int gbase = blockIdx.x * 128;
    const int h = blockIdx.y;
    const int bh = (gbase >> 12) * 16 + h;
    const int t = threadIdx.x, lane = t & 63, w = t >> 6;
    const int fr = lane & 15, fq = lane >> 4;

#pragma unroll
    for (int i = 0; i < 4; i++) {
        int idx = t + i * 256;                  // 0..1023
        int l = idx >> 3, d0 = (idx & 7) * 8;
        *(bf16x8*)(qs + l * 72 + d0) =
            *(const bf16x8*)(qfb + (size_t)(gbase + l) * 1024 + h * 64 + d0);
    }
#pragma unroll
    for (int i = 0; i < 2; i++) {
        int idx = t + i * 256;                  // 0..511
        int m = idx >> 3, d0 = (idx & 7) * 8;
        *(bf16x8*)(kvs + m * 72 + d0) =
            *(const bf16x8*)(kvb + (size_t)bh * 4096 + m * 64 + d0);
    }
    bf16x8 ksb[2];
#pragma unroll
    for (int kk = 0; kk < 2; kk++)
        ksb[kk] = *(const bf16x8*)(ksumb + bh * 64 + kk * 32 + fq * 8);
    __syncthreads();

    f32x4 acc[2][4], accz[2];
#pragma unroll
    for (int i = 0; i < 2; i++) {
        accz[i] = (f32x4){0.f, 0.f, 0.f, 0.f};
#pragma unroll
        for (int j = 0; j < 4; j++) acc[i][j] = (f32x4){0.f, 0.f, 0.f, 0.f};
    }

#pragma unroll
    for (int kk = 0; kk < 2; kk++) {
        bf16x8 af[2], bfr[4];
#pragma unroll
        for (int i = 0; i < 2; i++)
            af[i] = *(const bf16x8*)(qs + (32 * w + 16 * i + fr) * 72 + kk * 32 + fq * 8);
#pragma unroll
        for (int j = 0; j < 4; j++)
            bfr[j] = *(const bf16x8*)(kvs + (16 * j + fr) * 72 + kk * 32 + fq * 8);
#pragma unroll
        for (int i = 0; i < 2; i++) {
#pragma unroll
            for (int j = 0; j < 4; j++)
                acc[i][j] = __builtin_amdgcn_mfma_f32_16x16x32_bf16(
                    af[i], bfr[j], acc[i][j], 0, 0, 0);
            accz[i] = __builtin_amdgcn_mfma_f32_16x16x32_bf16(
                af[i], ksb[kk], accz[i], 0, 0, 0);
        }
    }

#pragma unroll
    for (int i = 0; i < 2; i++)
#pragma unroll
        for (int r = 0; r < 4; r++) {
            const float z = 1.0f / (accz[i][r] + 1e-6f);
            const int g = gbase + 32 * w + 16 * i + fq * 4 + r;
#pragma unroll
            for (int j = 0; j < 4; j++)
                yb[(size_t)g * 1024 + h * 64 + 16 * j + fr] =
                    (__bf16)(acc[i][j][r] * z);
        }
}

// ---------------------------------------------------------------------------
__global__ __launch_bounds__(256) void cast_x(const float* __restrict__ x,
                                              __bf16* __restrict__ xb)
{
    const size_t i = ((size_t)blockIdx.x * 256 + threadIdx.x) * 8;
    float4 a = *(const float4*)(x + i);
    float4 b = *(const float4*)(x + i + 4);
    bf16x8 o;
    o[0] = (__bf16)a.x; o[1] = (__bf16)a.y; o[2] = (__bf16)a.z; o[3] = (__bf16)a.w;
    o[4] = (__bf16)b.x; o[5] = (__bf16)b.y; o[6] = (__bf16)b.z; o[7] = (__bf16)b.w;
    *(bf16x8*)(xb + i) = o;
}

__global__ __launch_bounds__(256) void transpose_w(
    const float* __restrict__ w0, const float* __restrict__ w1,
    const float* __restrict__ w2, const float* __restrict__ w3,
    __bf16* __restrict__ o0, __bf16* __restrict__ o1,
    __bf16* __restrict__ o2, __bf16* __restrict__ o3)
{
    __shared__ float ld[32][33];
    const int wsel = blockIdx.z;
    const float* src = (wsel == 0) ? w0 : (wsel == 1) ? w1 : (wsel == 2) ? w2 : w3;
    __bf16* dst      = (wsel == 0) ? o0 : (wsel == 1) ? o1 : (wsel == 2) ? o2 : o3;

    const int kbase = blockIdx.x * 32;
    const int nbase = blockIdx.y * 32;
    const int t = threadIdx.x;
    const int r = t >> 3, c4 = (t & 7) * 4;

    float4 a = *(const float4*)(src + (size_t)(kbase + r) * 1024 + nbase + c4);
    ld[r][c4 + 0] = a.x; ld[r][c4 + 1] = a.y; ld[r][c4 + 2] = a.z; ld[r][c4 + 3] = a.w;
    __syncthreads();

    bf16x4 o;
    o[0] = (__bf16)ld[c4 + 0][r];
    o[1] = (__bf16)ld[c4 + 1][r];
    o[2] = (__bf16)ld[c4 + 2][r];
    o[3] = (__bf16)ld[c4 + 3][r];
    *(bf16x4*)(dst + (size_t)(nbase + r) * 1024 + kbase + c4) = o;
}

extern "C" void kernel_launch(void* const* d_in, const int* in_sizes, int n_in,
                              void* d_out, int out_size, void* d_ws, size_t ws_size,
                              hipStream_t stream)
{
    const float* x  = (const float*)d_in[0];
    const float* Wq = (const float*)d_in[1];
    const float* bq = (const float*)d_in[2];
    const float* Wk = (const float*)d_in[3];
    const float* bk = (const float*)d_in[4];
    const float* Wv = (const float*)d_in[5];
    const float* bv = (const float*)d_in[6];
    const float* Wo = (const float*)d_in[7];
    const float* bo = (const float*)d_in[8];
    float* out = (float*)d_out;

    __bf16* xb    = (__bf16*)d_ws;                   // 16777216
    __bf16* wqt   = xb + (size_t)16777216;           // 1048576 each
    __bf16* wkt   = wqt + 1048576;
    __bf16* wvt   = wkt + 1048576;
    __bf16* wot   = wvt + 1048576;
    __bf16* qfb   = wot + 1048576;                   // 16777216
    __bf16* kfb   = qfb + (size_t)16777216;          // 16777216 (reused as yb)
    __bf16* vb    = kfb + (size_t)16777216;          // 16777216
    float*  kvp   = (float*)(vb + (size_t)16777216); // 4194304 fp32 (16 MB)
    float*  ksp   = kvp + 4194304;                   // 65536 fp32
    __bf16* kvb   = (__bf16*)(ksp + 65536);          // 262144
    __bf16* ksumb = kvb + 262144;                    // 4096

    cast_x<<<dim3(8192), dim3(256), 0, stream>>>(x, xb);
    transpose_w<<<dim3(32, 32, 4), dim3(256), 0, stream>>>(
        Wq, Wk, Wv, Wo, wqt, wkt, wvt, wot);

    gemm_qkv_mfma<<<dim3(128, 24), dim3(256), 0, stream>>>(
        xb, wqt, wkt, wvt, bq, bk, bv, qfb, kfb, vb);
    kv_ksum_mfma<<<dim3(64, 16), dim3(256), 0, stream>>>(kfb, vb, kvp, ksp);
    reduce_kv<<<dim3(1040), dim3(256), 0, stream>>>(kvp, ksp, kvb, ksumb);
    y_mfma<<<dim3(128, 16), dim3(256), 0, stream>>>(qfb, kvb, ksumb, kfb);
    gemm_out_mfma<<<dim3(128, 8), dim3(256), 0, stream>>>(kfb, wot, bo, out);
}